// Round 5
// baseline (869.009 us; speedup 1.0000x reference)
//
#include <hip/hip_runtime.h>
#include <hip/hip_bf16.h>

// MC-Dropout eval-path masking: out[b, f] = in[b, f] * mask[f]
// in: (32768, 4096) fp32, mask: (4096,) fp32, out: (32768, 4096) fp32.
// Pure memory-bound streaming op: 512 MiB read + 512 MiB write per call
// (~1.07 GB HBM traffic; floor ~175 us at the ~6.2 TB/s this chip's fills
// achieve). Streams are read-once/write-once and >> L2, so use
// non-temporal (nt) accesses to skip cache allocation.

#define LAYER_SIZE 4096
#define MASK_VEC4  (LAYER_SIZE / 4)   // 1024 float4s per row

typedef float f32x4 __attribute__((ext_vector_type(4)));

__global__ void __launch_bounds__(256)
mcdropout_mask_kernel(const f32x4* __restrict__ in,
                      const f32x4* __restrict__ mask,
                      f32x4* __restrict__ out,
                      int n4) {
    const int stride = gridDim.x * blockDim.x;   // 524288 = 512 * 1024
    int i = blockIdx.x * blockDim.x + threadIdx.x;
    if (i >= n4) return;

    // stride is a multiple of MASK_VEC4 (1024), so the mask vec-index is
    // invariant across the grid-stride loop: hoist to one load per thread.
    const f32x4 m = mask[i & (MASK_VEC4 - 1)];

    // n4 = 2^25, total threads = 2^19 -> exactly 64 iterations per thread.
    // Unroll x4 for memory-level parallelism within the wave.
    #pragma unroll 4
    for (; i < n4; i += stride) {
        f32x4 v = __builtin_nontemporal_load(&in[i]);
        v *= m;
        __builtin_nontemporal_store(v, &out[i]);
    }
}

extern "C" void kernel_launch(void* const* d_in, const int* in_sizes, int n_in,
                              void* d_out, int out_size, void* d_ws, size_t ws_size,
                              hipStream_t stream) {
    const f32x4* in   = (const f32x4*)d_in[0];   // (32768, 4096) fp32
    const f32x4* mask = (const f32x4*)d_in[1];   // (4096,) fp32
    f32x4* out = (f32x4*)d_out;

    const int n4 = out_size / 4;                 // 33,554,432 float4s

    // 2048 blocks x 256 threads = 8192 waves = full residency (256 CU x 32
    // waves). Keep blocks*threads a multiple of 1024 or remove the
    // mask-hoist above.
    const int threads = 256;
    const int blocks  = 2048;
    mcdropout_mask_kernel<<<blocks, threads, 0, stream>>>(in, mask, out, n4);
}